// Round 2
// baseline (2357.483 us; speedup 1.0000x reference)
//
#include <hip/hip_runtime.h>

typedef __attribute__((ext_vector_type(4))) float f32x4;
typedef __attribute__((ext_vector_type(8))) __bf16 bf16x8;
typedef __attribute__((ext_vector_type(4))) float f32x4v;

#define BM 128
#define BK 64
#define TOTALW 4096

struct Args {
  const float* x;
  const float* W[8];
  float* out;
};

__device__ __forceinline__ bf16x8 cvt8(f32x4 a, f32x4 b) {
  bf16x8 r;
  r[0] = (__bf16)a.x; r[1] = (__bf16)a.y; r[2] = (__bf16)a.z; r[3] = (__bf16)a.w;
  r[4] = (__bf16)b.x; r[5] = (__bf16)b.y; r[6] = (__bf16)b.z; r[7] = (__bf16)b.w;
  return r;
}

// 32KB LDS/block -> 5 blocks/CU (160KB exactly); VGPR 92 <= 96 cap at 5 waves/SIMD
__global__ __launch_bounds__(256, 5) void ielin_kernel(Args args) {
  // bf16 LDS tiles, XOR-swizzled (16B granularity) to kill ds_read_b128 bank conflicts
  __shared__ __align__(16) ushort As[BM * BK];
  __shared__ __align__(16) ushort Bs[BM * BK];

  const int tid = threadIdx.x;
  const int bid = blockIdx.x;
  // XCD-aware bijective swizzle (8192 % 8 == 0): each XCD gets a contiguous chunk
  // of work-ids; the 32 column-tiles of one m-tile are consecutive on ONE XCD so
  // the 2MB fp32 A-panel stays L2-resident.
  const int work = (bid & 7) * 1024 + (bid >> 3);
  const int mt = work >> 5;   // m-tile 0..255
  const int c  = work & 31;   // 128-wide column tile 0..31

  // column tile -> block l (uniform scalar math, no tables)
  const int l = (c >= 1) + (c >= 2) + (c >= 5) + (c >= 8) + (c >= 13) + (c >= 18) + (c >= 25);
  const int pp = l >> 1, qq = l & 1;
  const int nirr = l | 1;                    // width_l / 128 = {1,1,3,3,5,5,7,7}
  const int cstart = 2 * pp * pp + qq * nirr;
  const int w  = nirr << 7;                  // K for this block
  const int sK = cstart << 7;                // column start of block in x/out
  const int noff = (c - cstart) << 7;        // row offset into W_l
  const float* __restrict__ Wl = args.W[l];

  // ---- staging coords: 256 threads, each owns 8 consecutive k per group, 4 groups per tile
  const int srow = tid >> 3;                 // 0..31
  const int sk   = (tid & 7) << 3;           // 0..56
  const float* ap = args.x + (size_t)(mt * BM + srow) * TOTALW + sK + sk;
  const float* bp = Wl + (size_t)(noff + srow) * w + sk;
  const size_t aStep = (size_t)32 * TOTALW;
  const size_t bStep = (size_t)32 * w;

  // ---- compute coords: 2x2 waves of 64x64, 4x4 fragments of 16x16x32
  const int lane = tid & 63;
  const int wid  = tid >> 6;
  const int wr = (wid >> 1) << 6;
  const int wc = (wid & 1) << 6;
  const int fr = lane & 15;                  // A-row / B-col within fragment
  const int kq = lane >> 4;                  // k-chunk of 8

  f32x4v acc[4][4] = {};

  f32x4 av[4][2], bv[4][2];
  const int nk = w >> 6;                     // 2..14 K-steps

  // prologue: load tile 0 into regs
  {
    const float* a = ap; const float* b = bp;
#pragma unroll
    for (int i = 0; i < 4; ++i) {
      av[i][0] = *(const f32x4*)(a); av[i][1] = *(const f32x4*)(a + 4); a += aStep;
      bv[i][0] = *(const f32x4*)(b); bv[i][1] = *(const f32x4*)(b + 4); b += bStep;
    }
  }

  for (int kt = 0; kt < nk; ++kt) {
    // convert + write current tile to LDS (swizzled)
#pragma unroll
    for (int i = 0; i < 4; ++i) {
      const int row = srow + 32 * i;
      const int e = (row * BK + sk) ^ ((row & 7) << 3);
      *(bf16x8*)&As[e] = cvt8(av[i][0], av[i][1]);
      *(bf16x8*)&Bs[e] = cvt8(bv[i][0], bv[i][1]);
    }
    __syncthreads();

    // issue next tile's global loads BEFORE compute so HBM latency hides under MFMA
    if (kt + 1 < nk) {
      const float* a = ap + (kt + 1) * BK;
      const float* b = bp + (kt + 1) * BK;
#pragma unroll
      for (int i = 0; i < 4; ++i) {
        av[i][0] = *(const f32x4*)(a); av[i][1] = *(const f32x4*)(a + 4); a += aStep;
        bv[i][0] = *(const f32x4*)(b); bv[i][1] = *(const f32x4*)(b + 4); b += bStep;
      }
    }

#pragma unroll
    for (int kk = 0; kk < 2; ++kk) {
      const int kb = kk * 32 + kq * 8;
      bf16x8 afr[4], bfr[4];
#pragma unroll
      for (int i = 0; i < 4; ++i) {
        const int ra = wr + i * 16 + fr;
        afr[i] = *(const bf16x8*)&As[(ra * BK + kb) ^ ((fr & 7) << 3)];
        const int rb = wc + i * 16 + fr;
        bfr[i] = *(const bf16x8*)&Bs[(rb * BK + kb) ^ ((fr & 7) << 3)];
      }
#pragma unroll
      for (int mi = 0; mi < 4; ++mi)
#pragma unroll
        for (int ni = 0; ni < 4; ++ni)
          acc[mi][ni] = __builtin_amdgcn_mfma_f32_16x16x32_bf16(afr[mi], bfr[ni], acc[mi][ni], 0, 0, 0);
    }
    __syncthreads();
  }

  // epilogue: C/D layout col=lane&15, row=(lane>>4)*4+reg  [m89-verified]
  float* op = args.out + (size_t)(mt * BM + wr + kq * 4) * TOTALW + (c << 7) + wc + fr;
#pragma unroll
  for (int mi = 0; mi < 4; ++mi) {
#pragma unroll
    for (int ni = 0; ni < 4; ++ni) {
      float* p = op + (size_t)(mi * 16) * TOTALW + ni * 16;
      p[0 * TOTALW] = acc[mi][ni][0];
      p[1 * TOTALW] = acc[mi][ni][1];
      p[2 * TOTALW] = acc[mi][ni][2];
      p[3 * TOTALW] = acc[mi][ni][3];
    }
  }
}

extern "C" void kernel_launch(void* const* d_in, const int* in_sizes, int n_in,
                              void* d_out, int out_size, void* d_ws, size_t ws_size,
                              hipStream_t stream) {
  Args args;
  args.x = (const float*)d_in[0];
  for (int i = 0; i < 8; ++i) args.W[i] = (const float*)d_in[1 + i];
  args.out = (float*)d_out;
  ielin_kernel<<<8192, 256, 0, stream>>>(args);
}

// Round 3
// 530.286 us; speedup vs baseline: 4.4457x; 4.4457x over previous
//
#include <hip/hip_runtime.h>

typedef __attribute__((ext_vector_type(4))) float f32x4;
typedef __attribute__((ext_vector_type(8))) __bf16 bf16x8;
typedef __attribute__((ext_vector_type(4))) float f32x4v;

#define BM 128
#define BK 64
#define TOTALW 4096
#define NROW 32768
static const size_t NXE = 134217728ull;          // NROW*TOTALW
static const size_t WTOT = 2752512ull;           // sum w^2

__device__ __forceinline__ bf16x8 cvt8(f32x4 a, f32x4 b) {
  bf16x8 r;
  r[0] = (__bf16)a.x; r[1] = (__bf16)a.y; r[2] = (__bf16)a.z; r[3] = (__bf16)a.w;
  r[4] = (__bf16)b.x; r[5] = (__bf16)b.y; r[6] = (__bf16)b.z; r[7] = (__bf16)b.w;
  return r;
}

// ---------------- pass 1: fp32 -> bf16 convert of x and all W into ws ----------------
struct CArgs { const float* x; const float* W[8]; ushort* ws; };

__global__ __launch_bounds__(256) void convert_kernel(CArgs a) {
  const size_t tot8 = (NXE + WTOT) >> 3;
  const size_t stride = (size_t)gridDim.x * blockDim.x;
  for (size_t i = (size_t)blockIdx.x * blockDim.x + threadIdx.x; i < tot8; i += stride) {
    const size_t e = i << 3;
    const float* src;
    if (e < NXE) {
      src = a.x + e;
    } else {
      const size_t ew = e - NXE;
      // W segment ends (elements): select-chain (no runtime-indexed array -> no scratch)
      int l = 0; size_t base = 0;
      if (ew >= 16384)   { l = 1; base = 16384; }
      if (ew >= 32768)   { l = 2; base = 32768; }
      if (ew >= 180224)  { l = 3; base = 180224; }
      if (ew >= 327680)  { l = 4; base = 327680; }
      if (ew >= 737280)  { l = 5; base = 737280; }
      if (ew >= 1146880) { l = 6; base = 1146880; }
      if (ew >= 1949696) { l = 7; base = 1949696; }
      const float* w = a.W[0];
      if (l == 1) w = a.W[1]; if (l == 2) w = a.W[2]; if (l == 3) w = a.W[3];
      if (l == 4) w = a.W[4]; if (l == 5) w = a.W[5]; if (l == 6) w = a.W[6];
      if (l == 7) w = a.W[7];
      src = w + (ew - base);
    }
    f32x4 v0 = *(const f32x4*)src;
    f32x4 v1 = *(const f32x4*)(src + 4);
    *(bf16x8*)(a.ws + e) = cvt8(v0, v1);
  }
}

// ---------------- pass 2: bf16 block-diagonal GEMM, global_load_lds + dbuf pipeline ----------------
struct GArgs { const ushort* xb; const ushort* Wb[8]; float* out; };

__device__ __forceinline__ void gl16(const ushort* g, ushort* l) {
  __builtin_amdgcn_global_load_lds(
      (const __attribute__((address_space(1))) void*)g,
      (__attribute__((address_space(3))) void*)l, 16, 0, 0);
}

__global__ __launch_bounds__(256, 2) void gemm_kernel(GArgs args) {
  // double-buffered bf16 tiles; 64KB -> 2 blocks/CU
  __shared__ __align__(16) ushort As[2][BM * BK];
  __shared__ __align__(16) ushort Bs[2][BM * BK];

  const int tid = threadIdx.x;
  const int bid = blockIdx.x;
  // XCD-aware swizzle: XCD k gets works k*1024..k*1024+1023 (32 whole m-tiles)
  const int work = (bid & 7) * 1024 + (bid >> 3);
  const int mt = work >> 5;
  const int c  = work & 31;

  const int l = (c >= 1) + (c >= 2) + (c >= 5) + (c >= 8) + (c >= 13) + (c >= 18) + (c >= 25);
  const int pp = l >> 1, qq = l & 1;
  const int nirr = l | 1;
  const int cstart = 2 * pp * pp + qq * nirr;
  const int w  = nirr << 7;
  const int sK = cstart << 7;
  const int noff = (c - cstart) << 7;
  const ushort* __restrict__ Wbl = args.Wb[l];

  // staging: lane i of wave wv covers LDS bytes r*4096 + tid*16; row = r*32 + (tid>>3)
  // source chunk XOR-permuted so the LINEAR lds write yields the swizzled layout (rule 21)
  const int trow = tid >> 3;
  const int schunk = (tid & 7) ^ (trow & 7);
  const ushort* aSrc = args.xb + (size_t)(mt * BM + trow) * TOTALW + sK + schunk * 8;
  const ushort* bSrc = Wbl + (size_t)(noff + trow) * w + schunk * 8;

  // compute coords: 2x2 waves of 64x64
  const int lane = tid & 63;
  const int wid  = tid >> 6;
  const int wr = (wid >> 1) << 6;
  const int wc = (wid & 1) << 6;
  const int fr = lane & 15;
  const int kq = lane >> 4;

  f32x4v acc[4][4] = {};
  const int nk = w >> 6;   // 2..14

#define STAGE(bi, kt)                                                              \
  {                                                                                \
    _Pragma("unroll")                                                              \
    for (int r = 0; r < 4; ++r)                                                    \
      gl16(aSrc + (size_t)r * 32 * TOTALW + (kt) * 64, &As[bi][r * 2048 + tid * 8]); \
    _Pragma("unroll")                                                              \
    for (int r = 0; r < 4; ++r)                                                    \
      gl16(bSrc + (size_t)r * 32 * w + (kt) * 64, &Bs[bi][r * 2048 + tid * 8]);    \
  }

  STAGE(0, 0);
  asm volatile("s_waitcnt vmcnt(0)" ::: "memory");
  __builtin_amdgcn_s_barrier();
  __builtin_amdgcn_sched_barrier(0);

  int cur = 0;
  for (int kt = 0; kt < nk; ++kt) {
    if (kt + 1 < nk) STAGE(cur ^ 1, kt + 1);

#pragma unroll
    for (int kk = 0; kk < 2; ++kk) {
      const int kb = kk * 32 + kq * 8;
      bf16x8 afr[4], bfr[4];
#pragma unroll
      for (int i = 0; i < 4; ++i) {
        const int ra = wr + i * 16 + fr;                  // ra&7 == fr&7
        afr[i] = *(const bf16x8*)&As[cur][(ra * BK + kb) ^ ((fr & 7) << 3)];
        const int rb = wc + i * 16 + fr;
        bfr[i] = *(const bf16x8*)&Bs[cur][(rb * BK + kb) ^ ((fr & 7) << 3)];
      }
#pragma unroll
      for (int mi = 0; mi < 4; ++mi)
#pragma unroll
        for (int ni = 0; ni < 4; ++ni)
          acc[mi][ni] = __builtin_amdgcn_mfma_f32_16x16x32_bf16(afr[mi], bfr[ni], acc[mi][ni], 0, 0, 0);
    }

    if (kt + 1 < nk) {
      __builtin_amdgcn_sched_barrier(0);
      asm volatile("s_waitcnt vmcnt(0) lgkmcnt(0)" ::: "memory");
      __builtin_amdgcn_s_barrier();
      __builtin_amdgcn_sched_barrier(0);
    }
    cur ^= 1;
  }

  // epilogue: C/D layout col=lane&15, row=(lane>>4)*4+reg  [m89-verified]
  float* op = args.out + (size_t)(mt * BM + wr + kq * 4) * TOTALW + (c << 7) + wc + fr;
#pragma unroll
  for (int mi = 0; mi < 4; ++mi) {
#pragma unroll
    for (int ni = 0; ni < 4; ++ni) {
      float* p = op + (size_t)(mi * 16) * TOTALW + ni * 16;
      p[0 * TOTALW] = acc[mi][ni][0];
      p[1 * TOTALW] = acc[mi][ni][1];
      p[2 * TOTALW] = acc[mi][ni][2];
      p[3 * TOTALW] = acc[mi][ni][3];
    }
  }
#undef STAGE
}

// ---------------- fallback (round-1 kernel, used only if ws too small) ----------------
struct FArgs { const float* x; const float* W[8]; float* out; };

__global__ __launch_bounds__(256, 2) void ielin_fb(FArgs args) {
  __shared__ __align__(16) ushort As[BM * BK];
  __shared__ __align__(16) ushort Bs[BM * BK];
  const int tid = threadIdx.x;
  const int bid = blockIdx.x;
  const int work = (bid & 7) * 1024 + (bid >> 3);
  const int mt = work >> 5;
  const int c  = work & 31;
  const int l = (c >= 1) + (c >= 2) + (c >= 5) + (c >= 8) + (c >= 13) + (c >= 18) + (c >= 25);
  const int pp = l >> 1, qq = l & 1;
  const int nirr = l | 1;
  const int cstart = 2 * pp * pp + qq * nirr;
  const int w  = nirr << 7;
  const int sK = cstart << 7;
  const int noff = (c - cstart) << 7;
  const float* __restrict__ Wl = args.W[l];
  const int srow = tid >> 3;
  const int sk   = (tid & 7) << 3;
  const float* ap = args.x + (size_t)(mt * BM + srow) * TOTALW + sK + sk;
  const float* bp = Wl + (size_t)(noff + srow) * w + sk;
  const size_t aStep = (size_t)32 * TOTALW;
  const size_t bStep = (size_t)32 * w;
  const int lane = tid & 63;
  const int wid  = tid >> 6;
  const int wr = (wid >> 1) << 6;
  const int wc = (wid & 1) << 6;
  const int fr = lane & 15;
  const int kq = lane >> 4;
  f32x4v acc[4][4] = {};
  f32x4 av[4][2], bv[4][2];
  const int nk = w >> 6;
  {
    const float* a = ap; const float* b = bp;
#pragma unroll
    for (int i = 0; i < 4; ++i) {
      av[i][0] = *(const f32x4*)(a); av[i][1] = *(const f32x4*)(a + 4); a += aStep;
      bv[i][0] = *(const f32x4*)(b); bv[i][1] = *(const f32x4*)(b + 4); b += bStep;
    }
  }
  for (int kt = 0; kt < nk; ++kt) {
#pragma unroll
    for (int i = 0; i < 4; ++i) {
      const int row = srow + 32 * i;
      const int e = (row * BK + sk) ^ ((row & 7) << 3);
      *(bf16x8*)&As[e] = cvt8(av[i][0], av[i][1]);
      *(bf16x8*)&Bs[e] = cvt8(bv[i][0], bv[i][1]);
    }
    __syncthreads();
    if (kt + 1 < nk) {
      const float* a = ap + (kt + 1) * BK;
      const float* b = bp + (kt + 1) * BK;
#pragma unroll
      for (int i = 0; i < 4; ++i) {
        av[i][0] = *(const f32x4*)(a); av[i][1] = *(const f32x4*)(a + 4); a += aStep;
        bv[i][0] = *(const f32x4*)(b); bv[i][1] = *(const f32x4*)(b + 4); b += bStep;
      }
    }
#pragma unroll
    for (int kk = 0; kk < 2; ++kk) {
      const int kb = kk * 32 + kq * 8;
      bf16x8 afr[4], bfr[4];
#pragma unroll
      for (int i = 0; i < 4; ++i) {
        const int ra = wr + i * 16 + fr;
        afr[i] = *(const bf16x8*)&As[(ra * BK + kb) ^ ((fr & 7) << 3)];
        const int rb = wc + i * 16 + fr;
        bfr[i] = *(const bf16x8*)&Bs[(rb * BK + kb) ^ ((fr & 7) << 3)];
      }
#pragma unroll
      for (int mi = 0; mi < 4; ++mi)
#pragma unroll
        for (int ni = 0; ni < 4; ++ni)
          acc[mi][ni] = __builtin_amdgcn_mfma_f32_16x16x32_bf16(afr[mi], bfr[ni], acc[mi][ni], 0, 0, 0);
    }
    __syncthreads();
  }
  float* op = args.out + (size_t)(mt * BM + wr + kq * 4) * TOTALW + (c << 7) + wc + fr;
#pragma unroll
  for (int mi = 0; mi < 4; ++mi) {
#pragma unroll
    for (int ni = 0; ni < 4; ++ni) {
      float* p = op + (size_t)(mi * 16) * TOTALW + ni * 16;
      p[0 * TOTALW] = acc[mi][ni][0];
      p[1 * TOTALW] = acc[mi][ni][1];
      p[2 * TOTALW] = acc[mi][ni][2];
      p[3 * TOTALW] = acc[mi][ni][3];
    }
  }
}

extern "C" void kernel_launch(void* const* d_in, const int* in_sizes, int n_in,
                              void* d_out, int out_size, void* d_ws, size_t ws_size,
                              hipStream_t stream) {
  const size_t need = (NXE + WTOT) * 2;
  if (ws_size >= need) {
    CArgs ca;
    ca.x = (const float*)d_in[0];
    for (int i = 0; i < 8; ++i) ca.W[i] = (const float*)d_in[1 + i];
    ca.ws = (ushort*)d_ws;
    convert_kernel<<<2048, 256, 0, stream>>>(ca);

    GArgs ga;
    ga.xb = (const ushort*)d_ws;
    static const size_t cumW[8] = {0, 16384, 32768, 180224, 327680, 737280, 1146880, 1949696};
    for (int i = 0; i < 8; ++i) ga.Wb[i] = (const ushort*)d_ws + NXE + cumW[i];
    ga.out = (float*)d_out;
    gemm_kernel<<<8192, 256, 0, stream>>>(ga);
  } else {
    FArgs fa;
    fa.x = (const float*)d_in[0];
    for (int i = 0; i < 8; ++i) fa.W[i] = (const float*)d_in[1 + i];
    fa.out = (float*)d_out;
    ielin_fb<<<8192, 256, 0, stream>>>(fa);
  }
}

// Round 4
// 521.977 us; speedup vs baseline: 4.5164x; 1.0159x over previous
//
#include <hip/hip_runtime.h>

typedef __attribute__((ext_vector_type(4))) float f32x4;
typedef __attribute__((ext_vector_type(8))) __bf16 bf16x8;
typedef __attribute__((ext_vector_type(4))) float f32x4v;

#define BM 128
#define BK 64
#define TOTALW 4096
#define NROW 32768
static const size_t NXE = 134217728ull;          // NROW*TOTALW
static const size_t WTOT = 2752512ull;           // sum w^2

__device__ __forceinline__ bf16x8 cvt8(f32x4 a, f32x4 b) {
  bf16x8 r;
  r[0] = (__bf16)a.x; r[1] = (__bf16)a.y; r[2] = (__bf16)a.z; r[3] = (__bf16)a.w;
  r[4] = (__bf16)b.x; r[5] = (__bf16)b.y; r[6] = (__bf16)b.z; r[7] = (__bf16)b.w;
  return r;
}

// ---------------- pass 1: fp32 -> bf16 convert of x and all W into ws ----------------
struct CArgs { const float* x; const float* W[8]; ushort* ws; };

__global__ __launch_bounds__(256) void convert_kernel(CArgs a) {
  const size_t tot8 = (NXE + WTOT) >> 3;
  const size_t stride = (size_t)gridDim.x * blockDim.x;
  for (size_t i = (size_t)blockIdx.x * blockDim.x + threadIdx.x; i < tot8; i += stride) {
    const size_t e = i << 3;
    const float* src;
    if (e < NXE) {
      src = a.x + e;
    } else {
      const size_t ew = e - NXE;
      int l = 0; size_t base = 0;
      if (ew >= 16384)   { l = 1; base = 16384; }
      if (ew >= 32768)   { l = 2; base = 32768; }
      if (ew >= 180224)  { l = 3; base = 180224; }
      if (ew >= 327680)  { l = 4; base = 327680; }
      if (ew >= 737280)  { l = 5; base = 737280; }
      if (ew >= 1146880) { l = 6; base = 1146880; }
      if (ew >= 1949696) { l = 7; base = 1949696; }
      const float* w = a.W[0];
      if (l == 1) w = a.W[1]; if (l == 2) w = a.W[2]; if (l == 3) w = a.W[3];
      if (l == 4) w = a.W[4]; if (l == 5) w = a.W[5]; if (l == 6) w = a.W[6];
      if (l == 7) w = a.W[7];
      src = w + (ew - base);
    }
    f32x4 v0 = *(const f32x4*)src;
    f32x4 v1 = *(const f32x4*)(src + 4);
    *(bf16x8*)(a.ws + e) = cvt8(v0, v1);
  }
}

// ---------------- pass 2: bf16 block-diagonal GEMM, counted-vmcnt dbuf pipeline ----------------
struct GArgs { const ushort* xb; const ushort* Wb[8]; float* out; };

__device__ __forceinline__ void gl16(const ushort* g, ushort* l) {
  __builtin_amdgcn_global_load_lds(
      (const __attribute__((address_space(1))) void*)g,
      (__attribute__((address_space(3))) void*)l, 16, 0, 0);
}

__global__ __launch_bounds__(256, 2) void gemm_kernel(GArgs args) {
  // double-buffered bf16 tiles; 64KB -> 2 blocks/CU
  __shared__ __align__(16) ushort As[2][BM * BK];
  __shared__ __align__(16) ushort Bs[2][BM * BK];

  const int tid = threadIdx.x;
  const int bid = blockIdx.x;
  // XCD-aware swizzle: XCD k gets works k*1024..k*1024+1023 (32 whole m-tiles)
  const int work = (bid & 7) * 1024 + (bid >> 3);
  const int mt = work >> 5;
  const int c  = work & 31;

  const int l = (c >= 1) + (c >= 2) + (c >= 5) + (c >= 8) + (c >= 13) + (c >= 18) + (c >= 25);
  const int pp = l >> 1, qq = l & 1;
  const int nirr = l | 1;
  const int cstart = 2 * pp * pp + qq * nirr;
  const int w  = nirr << 7;
  const int sK = cstart << 7;
  const int noff = (c - cstart) << 7;
  const ushort* __restrict__ Wbl = args.Wb[l];

  // staging: LINEAR lds dest (wave-uniform base + lane*16B); source chunk
  // XOR-permuted so the linear write yields the swizzled layout (rule 21)
  const int trow = tid >> 3;
  const int schunk = (tid & 7) ^ (trow & 7);
  const ushort* aSrc = args.xb + (size_t)(mt * BM + trow) * TOTALW + sK + schunk * 8;
  const ushort* bSrc = Wbl + (size_t)(noff + trow) * w + schunk * 8;

  // compute coords: 2x2 waves of 64x64
  const int lane = tid & 63;
  const int wid  = tid >> 6;
  const int wr = (wid >> 1) << 6;
  const int wc = (wid & 1) << 6;
  const int fr = lane & 15;
  const int kq = lane >> 4;

  f32x4v acc[4][4] = {};
  const int nk = w >> 6;   // 2..14

#define STAGE(bi, kt)                                                              \
  {                                                                                \
    _Pragma("unroll")                                                              \
    for (int r = 0; r < 4; ++r)                                                    \
      gl16(aSrc + (size_t)r * 32 * TOTALW + (kt) * 64, &As[bi][r * 2048 + tid * 8]); \
    _Pragma("unroll")                                                              \
    for (int r = 0; r < 4; ++r)                                                    \
      gl16(bSrc + (size_t)r * 32 * w + (kt) * 64, &Bs[bi][r * 2048 + tid * 8]);    \
  }

  STAGE(0, 0);

  int cur = 0;
  for (int kt = 0; kt < nk; ++kt) {
    // issue next tile's loads FIRST, then wait only for cur's 8 (counted vmcnt:
    // the 8 just-issued stay in flight across the barrier and the MFMA phase)
    if (kt + 1 < nk) {
      STAGE(cur ^ 1, kt + 1);
      asm volatile("s_waitcnt vmcnt(8)" ::: "memory");
    } else {
      asm volatile("s_waitcnt vmcnt(0)" ::: "memory");
    }
    __builtin_amdgcn_s_barrier();
    __builtin_amdgcn_sched_barrier(0);

#pragma unroll
    for (int kk = 0; kk < 2; ++kk) {
      const int kb = kk * 32 + kq * 8;
      bf16x8 afr[4], bfr[4];
#pragma unroll
      for (int i = 0; i < 4; ++i) {
        const int ra = wr + i * 16 + fr;                  // ra&7 == fr&7
        afr[i] = *(const bf16x8*)&As[cur][(ra * BK + kb) ^ ((fr & 7) << 3)];
        const int rb = wc + i * 16 + fr;
        bfr[i] = *(const bf16x8*)&Bs[cur][(rb * BK + kb) ^ ((fr & 7) << 3)];
      }
#pragma unroll
      for (int mi = 0; mi < 4; ++mi)
#pragma unroll
        for (int ni = 0; ni < 4; ++ni)
          acc[mi][ni] = __builtin_amdgcn_mfma_f32_16x16x32_bf16(afr[mi], bfr[ni], acc[mi][ni], 0, 0, 0);
    }

    if (kt + 1 < nk) {
      __builtin_amdgcn_sched_barrier(0);
      __builtin_amdgcn_s_barrier();      // all waves done reading cur before next STAGE overwrites
    }
    cur ^= 1;
  }

  // epilogue: C/D layout col=lane&15, row=(lane>>4)*4+reg  [m89-verified]
  float* op = args.out + (size_t)(mt * BM + wr + kq * 4) * TOTALW + (c << 7) + wc + fr;
#pragma unroll
  for (int mi = 0; mi < 4; ++mi) {
#pragma unroll
    for (int ni = 0; ni < 4; ++ni) {
      float* p = op + (size_t)(mi * 16) * TOTALW + ni * 16;
      p[0 * TOTALW] = acc[mi][ni][0];
      p[1 * TOTALW] = acc[mi][ni][1];
      p[2 * TOTALW] = acc[mi][ni][2];
      p[3 * TOTALW] = acc[mi][ni][3];
    }
  }
#undef STAGE
}

// ---------------- fallback (round-1 kernel, used only if ws too small) ----------------
struct FArgs { const float* x; const float* W[8]; float* out; };

__global__ __launch_bounds__(256, 2) void ielin_fb(FArgs args) {
  __shared__ __align__(16) ushort As[BM * BK];
  __shared__ __align__(16) ushort Bs[BM * BK];
  const int tid = threadIdx.x;
  const int bid = blockIdx.x;
  const int work = (bid & 7) * 1024 + (bid >> 3);
  const int mt = work >> 5;
  const int c  = work & 31;
  const int l = (c >= 1) + (c >= 2) + (c >= 5) + (c >= 8) + (c >= 13) + (c >= 18) + (c >= 25);
  const int pp = l >> 1, qq = l & 1;
  const int nirr = l | 1;
  const int cstart = 2 * pp * pp + qq * nirr;
  const int w  = nirr << 7;
  const int sK = cstart << 7;
  const int noff = (c - cstart) << 7;
  const float* __restrict__ Wl = args.W[l];
  const int srow = tid >> 3;
  const int sk   = (tid & 7) << 3;
  const float* ap = args.x + (size_t)(mt * BM + srow) * TOTALW + sK + sk;
  const float* bp = Wl + (size_t)(noff + srow) * w + sk;
  const size_t aStep = (size_t)32 * TOTALW;
  const size_t bStep = (size_t)32 * w;
  const int lane = tid & 63;
  const int wid  = tid >> 6;
  const int wr = (wid >> 1) << 6;
  const int wc = (wid & 1) << 6;
  const int fr = lane & 15;
  const int kq = lane >> 4;
  f32x4v acc[4][4] = {};
  f32x4 av[4][2], bv[4][2];
  const int nk = w >> 6;
  {
    const float* a = ap; const float* b = bp;
#pragma unroll
    for (int i = 0; i < 4; ++i) {
      av[i][0] = *(const f32x4*)(a); av[i][1] = *(const f32x4*)(a + 4); a += aStep;
      bv[i][0] = *(const f32x4*)(b); bv[i][1] = *(const f32x4*)(b + 4); b += bStep;
    }
  }
  for (int kt = 0; kt < nk; ++kt) {
#pragma unroll
    for (int i = 0; i < 4; ++i) {
      const int row = srow + 32 * i;
      const int e = (row * BK + sk) ^ ((row & 7) << 3);
      *(bf16x8*)&As[e] = cvt8(av[i][0], av[i][1]);
      *(bf16x8*)&Bs[e] = cvt8(bv[i][0], bv[i][1]);
    }
    __syncthreads();
    if (kt + 1 < nk) {
      const float* a = ap + (kt + 1) * BK;
      const float* b = bp + (kt + 1) * BK;
#pragma unroll
      for (int i = 0; i < 4; ++i) {
        av[i][0] = *(const f32x4*)(a); av[i][1] = *(const f32x4*)(a + 4); a += aStep;
        bv[i][0] = *(const f32x4*)(b); bv[i][1] = *(const f32x4*)(b + 4); b += bStep;
      }
    }
#pragma unroll
    for (int kk = 0; kk < 2; ++kk) {
      const int kb = kk * 32 + kq * 8;
      bf16x8 afr[4], bfr[4];
#pragma unroll
      for (int i = 0; i < 4; ++i) {
        const int ra = wr + i * 16 + fr;
        afr[i] = *(const bf16x8*)&As[(ra * BK + kb) ^ ((fr & 7) << 3)];
        const int rb = wc + i * 16 + fr;
        bfr[i] = *(const bf16x8*)&Bs[(rb * BK + kb) ^ ((fr & 7) << 3)];
      }
#pragma unroll
      for (int mi = 0; mi < 4; ++mi)
#pragma unroll
        for (int ni = 0; ni < 4; ++ni)
          acc[mi][ni] = __builtin_amdgcn_mfma_f32_16x16x32_bf16(afr[mi], bfr[ni], acc[mi][ni], 0, 0, 0);
    }
    __syncthreads();
  }
  float* op = args.out + (size_t)(mt * BM + wr + kq * 4) * TOTALW + (c << 7) + wc + fr;
#pragma unroll
  for (int mi = 0; mi < 4; ++mi) {
#pragma unroll
    for (int ni = 0; ni < 4; ++ni) {
      float* p = op + (size_t)(mi * 16) * TOTALW + ni * 16;
      p[0 * TOTALW] = acc[mi][ni][0];
      p[1 * TOTALW] = acc[mi][ni][1];
      p[2 * TOTALW] = acc[mi][ni][2];
      p[3 * TOTALW] = acc[mi][ni][3];
    }
  }
}

extern "C" void kernel_launch(void* const* d_in, const int* in_sizes, int n_in,
                              void* d_out, int out_size, void* d_ws, size_t ws_size,
                              hipStream_t stream) {
  const size_t need = (NXE + WTOT) * 2;
  if (ws_size >= need) {
    CArgs ca;
    ca.x = (const float*)d_in[0];
    for (int i = 0; i < 8; ++i) ca.W[i] = (const float*)d_in[1 + i];
    ca.ws = (ushort*)d_ws;
    convert_kernel<<<4096, 256, 0, stream>>>(ca);

    GArgs ga;
    ga.xb = (const ushort*)d_ws;
    static const size_t cumW[8] = {0, 16384, 32768, 180224, 327680, 737280, 1146880, 1949696};
    for (int i = 0; i < 8; ++i) ga.Wb[i] = (const ushort*)d_ws + NXE + cumW[i];
    ga.out = (float*)d_out;
    gemm_kernel<<<8192, 256, 0, stream>>>(ga);
  } else {
    FArgs fa;
    fa.x = (const float*)d_in[0];
    for (int i = 0; i < 8; ++i) fa.W[i] = (const float*)d_in[1 + i];
    fa.out = (float*)d_out;
    ielin_fb<<<8192, 256, 0, stream>>>(fa);
  }
}

// Round 6
// 478.629 us; speedup vs baseline: 4.9255x; 1.0906x over previous
//
#include <hip/hip_runtime.h>

typedef __attribute__((ext_vector_type(4))) float f32x4;
typedef __attribute__((ext_vector_type(8))) __bf16 bf16x8;
typedef __attribute__((ext_vector_type(4))) float f32x4v;

#define BM 128
#define BK 64
#define TOTALW 4096
#define NROW 32768
static const size_t NXE = 134217728ull;          // NROW*TOTALW
static const size_t WTOT = 2752512ull;           // sum w^2

__device__ __forceinline__ bf16x8 cvt8(f32x4 a, f32x4 b) {
  bf16x8 r;
  r[0] = (__bf16)a.x; r[1] = (__bf16)a.y; r[2] = (__bf16)a.z; r[3] = (__bf16)a.w;
  r[4] = (__bf16)b.x; r[5] = (__bf16)b.y; r[6] = (__bf16)b.z; r[7] = (__bf16)b.w;
  return r;
}

// ---------------- pass 1: fp32 -> bf16 convert of x and all W into ws ----------------
struct CArgs { const float* x; const float* W[8]; ushort* ws; };

__global__ __launch_bounds__(256) void convert_kernel(CArgs a) {
  const size_t tot8 = (NXE + WTOT) >> 3;
  const size_t stride = (size_t)gridDim.x * blockDim.x;
  for (size_t i = (size_t)blockIdx.x * blockDim.x + threadIdx.x; i < tot8; i += stride) {
    const size_t e = i << 3;
    const float* src;
    if (e < NXE) {
      src = a.x + e;
    } else {
      const size_t ew = e - NXE;
      int l = 0; size_t base = 0;
      if (ew >= 16384)   { l = 1; base = 16384; }
      if (ew >= 32768)   { l = 2; base = 32768; }
      if (ew >= 180224)  { l = 3; base = 180224; }
      if (ew >= 327680)  { l = 4; base = 327680; }
      if (ew >= 737280)  { l = 5; base = 737280; }
      if (ew >= 1146880) { l = 6; base = 1146880; }
      if (ew >= 1949696) { l = 7; base = 1949696; }
      const float* w = a.W[0];
      if (l == 1) w = a.W[1]; if (l == 2) w = a.W[2]; if (l == 3) w = a.W[3];
      if (l == 4) w = a.W[4]; if (l == 5) w = a.W[5]; if (l == 6) w = a.W[6];
      if (l == 7) w = a.W[7];
      src = w + (ew - base);
    }
    f32x4 v0 = *(const f32x4*)src;
    f32x4 v1 = *(const f32x4*)(src + 4);
    *(bf16x8*)(a.ws + e) = cvt8(v0, v1);
  }
}

// ---------------- pass 2: bf16 block-diagonal GEMM, m97 structure ----------------
// Single-buffered 32KB LDS + __syncthreads loop: VGPR 88 + 32KB LDS -> up to
// 5 blocks/CU; implicit wave-level TLP across blocks does the load/compute
// overlap (m97/m114 evidence) instead of explicit dbuf (which capped us at 2
// blocks/CU and left every pipe <50% busy).
struct GArgs { const ushort* xb; const ushort* Wb[8]; float* out; };

__device__ __forceinline__ void gl16(const ushort* g, ushort* l) {
  __builtin_amdgcn_global_load_lds(
      (const __attribute__((address_space(1))) void*)g,
      (__attribute__((address_space(3))) void*)l, 16, 0, 0);
}

__global__ __launch_bounds__(256, 2) void gemm_kernel(GArgs args) {
  __shared__ __align__(16) ushort As[BM * BK];
  __shared__ __align__(16) ushort Bs[BM * BK];

  const int tid = threadIdx.x;
  const int bid = blockIdx.x;
  // XCD-aware swizzle: XCD k gets works k*1024..k*1024+1023 (32 whole m-tiles)
  const int work = (bid & 7) * 1024 + (bid >> 3);
  const int mt = work >> 5;
  // heavy-first: reverse column order so nk=14 blocks dispatch before nk=2,
  // shrinking the tail and grouping same-W blocks temporally for L2
  const int c  = 31 - (work & 31);

  const int l = (c >= 1) + (c >= 2) + (c >= 5) + (c >= 8) + (c >= 13) + (c >= 18) + (c >= 25);
  const int pp = l >> 1, qq = l & 1;
  const int nirr = l | 1;
  const int cstart = 2 * pp * pp + qq * nirr;
  const int w  = nirr << 7;
  const int sK = cstart << 7;
  const int noff = (c - cstart) << 7;
  const ushort* __restrict__ Wbl = args.Wb[l];

  // staging: LINEAR lds dest (wave-uniform base + lane*16B); source chunk
  // XOR-permuted so the linear write yields the swizzled layout (rule 21)
  const int trow = tid >> 3;
  const int schunk = (tid & 7) ^ (trow & 7);
  const ushort* aSrc = args.xb + (size_t)(mt * BM + trow) * TOTALW + sK + schunk * 8;
  const ushort* bSrc = Wbl + (size_t)(noff + trow) * w + schunk * 8;

  // compute coords: 2x2 waves of 64x64
  const int lane = tid & 63;
  const int wid  = tid >> 6;
  const int wr = (wid >> 1) << 6;
  const int wc = (wid & 1) << 6;
  const int fr = lane & 15;
  const int kq = lane >> 4;

  f32x4v acc[4][4] = {};
  const int nk = w >> 6;   // 2..14

  for (int kt = 0; kt < nk; ++kt) {
#pragma unroll
    for (int r = 0; r < 4; ++r)
      gl16(aSrc + (size_t)r * 32 * TOTALW + kt * 64, &As[r * 2048 + tid * 8]);
#pragma unroll
    for (int r = 0; r < 4; ++r)
      gl16(bSrc + (size_t)r * 32 * w + kt * 64, &Bs[r * 2048 + tid * 8]);

    asm volatile("s_waitcnt vmcnt(0)" ::: "memory");
    __syncthreads();

#pragma unroll
    for (int kk = 0; kk < 2; ++kk) {
      const int kb = kk * 32 + kq * 8;
      bf16x8 afr[4], bfr[4];
#pragma unroll
      for (int i = 0; i < 4; ++i) {
        const int ra = wr + i * 16 + fr;                  // ra&7 == fr&7
        afr[i] = *(const bf16x8*)&As[(ra * BK + kb) ^ ((fr & 7) << 3)];
        const int rb = wc + i * 16 + fr;
        bfr[i] = *(const bf16x8*)&Bs[(rb * BK + kb) ^ ((fr & 7) << 3)];
      }
#pragma unroll
      for (int mi = 0; mi < 4; ++mi)
#pragma unroll
        for (int ni = 0; ni < 4; ++ni)
          acc[mi][ni] = __builtin_amdgcn_mfma_f32_16x16x32_bf16(afr[mi], bfr[ni], acc[mi][ni], 0, 0, 0);
    }

    if (kt + 1 < nk) __syncthreads();   // all waves done reading before next STAGE overwrites
  }

  // epilogue: C/D layout col=lane&15, row=(lane>>4)*4+reg  [m89-verified]
  float* op = args.out + (size_t)(mt * BM + wr + kq * 4) * TOTALW + (c << 7) + wc + fr;
#pragma unroll
  for (int mi = 0; mi < 4; ++mi) {
#pragma unroll
    for (int ni = 0; ni < 4; ++ni) {
      float* p = op + (size_t)(mi * 16) * TOTALW + ni * 16;
      p[0 * TOTALW] = acc[mi][ni][0];
      p[1 * TOTALW] = acc[mi][ni][1];
      p[2 * TOTALW] = acc[mi][ni][2];
      p[3 * TOTALW] = acc[mi][ni][3];
    }
  }
}

// ---------------- fallback (round-1 kernel, used only if ws too small) ----------------
struct FArgs { const float* x; const float* W[8]; float* out; };

__global__ __launch_bounds__(256, 2) void ielin_fb(FArgs args) {
  __shared__ __align__(16) ushort As[BM * BK];
  __shared__ __align__(16) ushort Bs[BM * BK];
  const int tid = threadIdx.x;
  const int bid = blockIdx.x;
  const int work = (bid & 7) * 1024 + (bid >> 3);
  const int mt = work >> 5;
  const int c  = work & 31;
  const int l = (c >= 1) + (c >= 2) + (c >= 5) + (c >= 8) + (c >= 13) + (c >= 18) + (c >= 25);
  const int pp = l >> 1, qq = l & 1;
  const int nirr = l | 1;
  const int cstart = 2 * pp * pp + qq * nirr;
  const int w  = nirr << 7;
  const int sK = cstart << 7;
  const int noff = (c - cstart) << 7;
  const float* __restrict__ Wl = args.W[l];
  const int srow = tid >> 3;
  const int sk   = (tid & 7) << 3;
  const float* ap = args.x + (size_t)(mt * BM + srow) * TOTALW + sK + sk;
  const float* bp = Wl + (size_t)(noff + srow) * w + sk;
  const size_t aStep = (size_t)32 * TOTALW;
  const size_t bStep = (size_t)32 * w;
  const int lane = tid & 63;
  const int wid  = tid >> 6;
  const int wr = (wid >> 1) << 6;
  const int wc = (wid & 1) << 6;
  const int fr = lane & 15;
  const int kq = lane >> 4;
  f32x4v acc[4][4] = {};
  f32x4 av[4][2], bv[4][2];
  const int nk = w >> 6;
  {
    const float* a = ap; const float* b = bp;
#pragma unroll
    for (int i = 0; i < 4; ++i) {
      av[i][0] = *(const f32x4*)(a); av[i][1] = *(const f32x4*)(a + 4); a += aStep;
      bv[i][0] = *(const f32x4*)(b); bv[i][1] = *(const f32x4*)(b + 4); b += bStep;
    }
  }
  for (int kt = 0; kt < nk; ++kt) {
#pragma unroll
    for (int i = 0; i < 4; ++i) {
      const int row = srow + 32 * i;
      const int e = (row * BK + sk) ^ ((row & 7) << 3);
      *(bf16x8*)&As[e] = cvt8(av[i][0], av[i][1]);
      *(bf16x8*)&Bs[e] = cvt8(bv[i][0], bv[i][1]);
    }
    __syncthreads();
    if (kt + 1 < nk) {
      const float* a = ap + (kt + 1) * BK;
      const float* b = bp + (kt + 1) * BK;
#pragma unroll
      for (int i = 0; i < 4; ++i) {
        av[i][0] = *(const f32x4*)(a); av[i][1] = *(const f32x4*)(a + 4); a += aStep;
        bv[i][0] = *(const f32x4*)(b); bv[i][1] = *(const f32x4*)(b + 4); b += bStep;
      }
    }
#pragma unroll
    for (int kk = 0; kk < 2; ++kk) {
      const int kb = kk * 32 + kq * 8;
      bf16x8 afr[4], bfr[4];
#pragma unroll
      for (int i = 0; i < 4; ++i) {
        const int ra = wr + i * 16 + fr;
        afr[i] = *(const bf16x8*)&As[(ra * BK + kb) ^ ((fr & 7) << 3)];
        const int rb = wc + i * 16 + fr;
        bfr[i] = *(const bf16x8*)&Bs[(rb * BK + kb) ^ ((fr & 7) << 3)];
      }
#pragma unroll
      for (int mi = 0; mi < 4; ++mi)
#pragma unroll
        for (int ni = 0; ni < 4; ++ni)
          acc[mi][ni] = __builtin_amdgcn_mfma_f32_16x16x32_bf16(afr[mi], bfr[ni], acc[mi][ni], 0, 0, 0);
    }
    __syncthreads();
  }
  float* op = args.out + (size_t)(mt * BM + wr + kq * 4) * TOTALW + (c << 7) + wc + fr;
#pragma unroll
  for (int mi = 0; mi < 4; ++mi) {
#pragma unroll
    for (int ni = 0; ni < 4; ++ni) {
      float* p = op + (size_t)(mi * 16) * TOTALW + ni * 16;
      p[0 * TOTALW] = acc[mi][ni][0];
      p[1 * TOTALW] = acc[mi][ni][1];
      p[2 * TOTALW] = acc[mi][ni][2];
      p[3 * TOTALW] = acc[mi][ni][3];
    }
  }
}

extern "C" void kernel_launch(void* const* d_in, const int* in_sizes, int n_in,
                              void* d_out, int out_size, void* d_ws, size_t ws_size,
                              hipStream_t stream) {
  const size_t need = (NXE + WTOT) * 2;
  if (ws_size >= need) {
    CArgs ca;
    ca.x = (const float*)d_in[0];
    for (int i = 0; i < 8; ++i) ca.W[i] = (const float*)d_in[1 + i];
    ca.ws = (ushort*)d_ws;
    convert_kernel<<<4096, 256, 0, stream>>>(ca);

    GArgs ga;
    ga.xb = (const ushort*)d_ws;
    static const size_t cumW[8] = {0, 16384, 32768, 180224, 327680, 737280, 1146880, 1949696};
    for (int i = 0; i < 8; ++i) ga.Wb[i] = (const ushort*)d_ws + NXE + cumW[i];
    ga.out = (float*)d_out;
    gemm_kernel<<<8192, 256, 0, stream>>>(ga);
  } else {
    FArgs fa;
    fa.x = (const float*)d_in[0];
    for (int i = 0; i < 8; ++i) fa.W[i] = (const float*)d_in[1 + i];
    fa.out = (float*)d_out;
    ielin_fb<<<8192, 256, 0, stream>>>(fa);
  }
}